// Round 1
// baseline (583.538 us; speedup 1.0000x reference)
//
#include <hip/hip_runtime.h>

// Problem constants (fixed by the reference):
// x: (B=16, C=256, W=64, P=128) fp32 ; codebooks: (NS=4, K=256, SC=64) fp32
#define NSQ 4
#define KCB 256
#define SCH 64
#define BB  16
#define WW  64
#define PP  128
#define NVEC (BB*WW*PP)          // 131072 vectors per subspace
#define TILES_PER_BLOCK 8
#define BLOCKS_PER_S (NVEC/64/TILES_PER_BLOCK)   // 256

// ---------------------------------------------------------------------------
// Pass 1: for each (s, n) compute argmin_k ( ||cb[s,k]||^2 - 2 * x_n . cb[s,k] )
// Block: 256 threads, covers 64 n x 256 k per tile, 8 tiles per block.
// cbt LDS layout: [j][col] with col = (k & ~15) | ((k&15) ^ swz(k>>4)),
// swz(tk) = ((tk ^ (tk>>2)) & 3) << 2  -> b128 column reads are 2-way/bank (free).
// ---------------------------------------------------------------------------
__global__ __launch_bounds__(256) void pq_pass1(const float* __restrict__ x,
                                                const float* __restrict__ cb,
                                                int* __restrict__ idx_out)
{
    __shared__ float cbt[64][256];          // exactly 64 KiB
    const int tid = threadIdx.x;
    const int s   = blockIdx.x >> 8;        // / BLOCKS_PER_S
    const int blk = blockIdx.x & (BLOCKS_PER_S - 1);
    const int tk  = tid & 15;               // k-group: k = tk*16 + kk
    const int tn  = tid >> 4;               // n-group: n = base + tn*4 + nn
    const int swz = ((tk ^ (tk >> 2)) & 3) << 2;

    // ---- stage codebook (swizzled), one row k per thread ----
    {
        const int k    = tid;
        const int tks  = k >> 4;
        const int swzs = ((tks ^ (tks >> 2)) & 3) << 2;
        const int col  = (k & ~15) | ((k & 15) ^ swzs);
        const float* row = cb + (size_t)(s * KCB + k) * SCH;
#pragma unroll
        for (int j4 = 0; j4 < 16; ++j4) {
            float4 v = *(const float4*)(row + j4 * 4);
            cbt[j4*4 + 0][col] = v.x;
            cbt[j4*4 + 1][col] = v.y;
            cbt[j4*4 + 2][col] = v.z;
            cbt[j4*4 + 3][col] = v.w;
        }
    }
    __syncthreads();

    const int cb0 = (tk << 4) | (0  ^ swz);
    const int cb1 = (tk << 4) | (4  ^ swz);
    const int cb2 = (tk << 4) | (8  ^ swz);
    const int cb3 = (tk << 4) | (12 ^ swz);

    // ---- per-thread codebook norms for its 16 k (registers) ----
    float cn[16];
#pragma unroll
    for (int kk = 0; kk < 16; ++kk) cn[kk] = 0.f;
    for (int j = 0; j < 64; ++j) {
        float c[16];
        {
            float4 t0 = *(const float4*)&cbt[j][cb0];
            float4 t1 = *(const float4*)&cbt[j][cb1];
            float4 t2 = *(const float4*)&cbt[j][cb2];
            float4 t3 = *(const float4*)&cbt[j][cb3];
            c[0]=t0.x; c[1]=t0.y; c[2]=t0.z; c[3]=t0.w;
            c[4]=t1.x; c[5]=t1.y; c[6]=t1.z; c[7]=t1.w;
            c[8]=t2.x; c[9]=t2.y; c[10]=t2.z; c[11]=t2.w;
            c[12]=t3.x; c[13]=t3.y; c[14]=t3.z; c[15]=t3.w;
        }
#pragma unroll
        for (int kk = 0; kk < 16; ++kk) cn[kk] = fmaf(c[kk], c[kk], cn[kk]);
    }

    // ---- n-tiles ----
    for (int t = 0; t < TILES_PER_BLOCK; ++t) {
        const int n_base = blk * (TILES_PER_BLOCK * 64) + t * 64;
        const int b  = n_base >> 13;          // / (W*P)
        const int w  = (n_base >> 7) & 63;
        const int p0 = n_base & 127;          // multiple of 64
        // x[b, s*64+j, w, p0 + 4*tn + nn], row j stride = W*P = 8192 floats
        const float* xp = x + ((size_t)((b * 256 + s * 64) * 64 + w)) * 128 + p0 + 4 * tn;

        float acc[4][16];
#pragma unroll
        for (int nn = 0; nn < 4; ++nn)
#pragma unroll
            for (int kk = 0; kk < 16; ++kk) acc[nn][kk] = 0.f;

#pragma unroll 2
        for (int j = 0; j < 64; ++j) {
            float4 xv = *(const float4*)(xp + (size_t)j * 8192);
            float c[16];
            {
                float4 t0 = *(const float4*)&cbt[j][cb0];
                float4 t1 = *(const float4*)&cbt[j][cb1];
                float4 t2 = *(const float4*)&cbt[j][cb2];
                float4 t3 = *(const float4*)&cbt[j][cb3];
                c[0]=t0.x; c[1]=t0.y; c[2]=t0.z; c[3]=t0.w;
                c[4]=t1.x; c[5]=t1.y; c[6]=t1.z; c[7]=t1.w;
                c[8]=t2.x; c[9]=t2.y; c[10]=t2.z; c[11]=t2.w;
                c[12]=t3.x; c[13]=t3.y; c[14]=t3.z; c[15]=t3.w;
            }
#pragma unroll
            for (int kk = 0; kk < 16; ++kk) {
                acc[0][kk] = fmaf(xv.x, c[kk], acc[0][kk]);
                acc[1][kk] = fmaf(xv.y, c[kk], acc[1][kk]);
                acc[2][kk] = fmaf(xv.z, c[kk], acc[2][kk]);
                acc[3][kk] = fmaf(xv.w, c[kk], acc[3][kk]);
            }
        }

        // ---- per-thread argmin over its 16 k (first-index tie-break) ----
        float best[4] = {3.4e38f, 3.4e38f, 3.4e38f, 3.4e38f};
        int   bidx[4] = {0, 0, 0, 0};
#pragma unroll
        for (int kk = 0; kk < 16; ++kk) {
            const int k = (tk << 4) + kk;
#pragma unroll
            for (int nn = 0; nn < 4; ++nn) {
                float d = fmaf(-2.f, acc[nn][kk], cn[kk]);
                bool better = (d < best[nn]);
                best[nn] = better ? d : best[nn];
                bidx[nn] = better ? k : bidx[nn];
            }
        }
        // ---- reduce across the 16 tk-threads (lanes tid&15, same wave) ----
#pragma unroll
        for (int m = 8; m; m >>= 1) {
#pragma unroll
            for (int nn = 0; nn < 4; ++nn) {
                float ob = __shfl_xor(best[nn], m, 64);
                int   oi = __shfl_xor(bidx[nn], m, 64);
                bool take = (ob < best[nn]) || (ob == best[nn] && oi < bidx[nn]);
                best[nn] = take ? ob : best[nn];
                bidx[nn] = take ? oi : bidx[nn];
            }
        }
        if (tk == 0) {
            int4 r; r.x = bidx[0]; r.y = bidx[1]; r.z = bidx[2]; r.w = bidx[3];
            *(int4*)(idx_out + (size_t)s * NVEC + n_base + 4 * tn) = r;
        }
        // no __syncthreads needed: cbt is read-only after staging
    }
}

// ---------------------------------------------------------------------------
// Pass 2: out[b, c, w, p] = cb[s, idx[s, b*8192 + p*64 + w], c&63],  s = c>>6
// One block per (b,c): stage idx slice transposed in LDS + codebook column,
// write 8192 floats coalesced (float4).
// ---------------------------------------------------------------------------
__global__ __launch_bounds__(256) void pq_pass2(const float* __restrict__ cb,
                                                const int* __restrict__ idx,
                                                float* __restrict__ out)
{
    __shared__ int   L[64][132];      // [w][p], row stride 132 (16B aligned, pad)
    __shared__ float cbc[256];
    const int tid = threadIdx.x;
    const int bc  = blockIdx.x;       // b*256 + c
    const int b   = bc >> 8;
    const int c   = bc & 255;
    const int s   = c >> 6;
    const int j   = c & 63;

    cbc[tid] = cb[(size_t)(s * KCB + tid) * SCH + j];

    const int* ip = idx + (size_t)s * NVEC + b * 8192;
#pragma unroll
    for (int r = 0; r < 32; ++r) {
        int g = r * 256 + tid;        // g = p*64 + w
        L[g & 63][g >> 6] = ip[g];
    }
    __syncthreads();

    float* op = out + (size_t)bc * 8192;
#pragma unroll
    for (int r = 0; r < 8; ++r) {
        int e4  = (r * 256 + tid) * 4;        // linear w*128 + p, 4-wide
        int w_o = e4 >> 7;
        int p_o = e4 & 127;
        int4 kv = *(const int4*)&L[w_o][p_o];
        float4 v;
        v.x = cbc[kv.x];
        v.y = cbc[kv.y];
        v.z = cbc[kv.z];
        v.w = cbc[kv.w];
        *(float4*)(op + e4) = v;
    }
}

extern "C" void kernel_launch(void* const* d_in, const int* in_sizes, int n_in,
                              void* d_out, int out_size, void* d_ws, size_t ws_size,
                              hipStream_t stream) {
    (void)in_sizes; (void)n_in; (void)out_size; (void)ws_size;
    const float* x   = (const float*)d_in[0];
    const float* cbk = (const float*)d_in[1];
    float*       out = (float*)d_out;
    int*         idx = (int*)d_ws;            // needs NSQ*NVEC*4 = 2 MiB scratch

    pq_pass1<<<NSQ * BLOCKS_PER_S, 256, 0, stream>>>(x, cbk, idx);
    pq_pass2<<<BB * 256, 256, 0, stream>>>(cbk, idx, out);
}